// Round 3
// baseline (213.422 us; speedup 1.0000x reference)
//
#include <hip/hip_runtime.h>
#include <hip/hip_bf16.h>

typedef __bf16 bf16x8 __attribute__((ext_vector_type(8)));
typedef float  f32x4  __attribute__((ext_vector_type(4)));

constexpr int B = 8, N = 4096, T = 128, D = 32;
constexpr float GAMMA = 0.001f;
constexpr float LOG2E = 1.4426950408889634f;
constexpr float K2 = -GAMMA * LOG2E;   // coeff on sq1 / sq2 (log2 domain)
constexpr float M2 = -2.0f * K2;       // coeff on dot

__device__ __forceinline__ float exp2_fast(float t) {
#if __has_builtin(__builtin_amdgcn_exp2f)
  return __builtin_amdgcn_exp2f(t);
#else
  return exp2f(t);
#endif
}

// ---------------------------------------------------------------------------
// Kernel 1 (MFMA proj): p1' = M2*(x@W1+b1) bf16, p2 = x@W2+b2 bf16,
// s1 = K2*||p1||^2, e2 = 0.125*exp2(K2*||p2||^2).
// W fragments staged ONCE per block into LDS in frag-ready layout
// (round-2 did the 128-scalar gather per wave -> 4x more gather instrs).
// ---------------------------------------------------------------------------
__global__ __launch_bounds__(256, 2) void proj_mfma(
    const float* __restrict__ x,  const float* __restrict__ W1,
    const float* __restrict__ b1, const float* __restrict__ W2,
    const float* __restrict__ b2,
    __bf16* __restrict__ p1b, __bf16* __restrict__ p2b,
    float* __restrict__ s1, float* __restrict__ e2) {
  __shared__ bf16x8 wlds[4][4][64];   // 16 KB, frag-ready
  const int tid  = threadIdx.x;
  const int lane = tid & 63;
  const int wid  = tid >> 6;
  const int lr   = lane & 15;
  const int lk   = lane >> 4;
  const int r0   = blockIdx.x * 64 + wid * 16;   // 0 .. B*N-1

  // cooperative W-frag fill: 1024 entries, 4 per thread
  #pragma unroll
  for (int t = 0; t < 4; ++t) {
    const int e  = tid + t * 256;
    const int c  = e >> 8;
    const int s  = (e >> 6) & 3;
    const int ln = e & 63;
    const int llr = ln & 15, llk = ln >> 4;
    const float* Wp = (c < 2) ? W1 : W2;
    const int cc = (c * 16 + llr) & 31;
    bf16x8 v;
    #pragma unroll
    for (int j = 0; j < 8; ++j)
      v[j] = (__bf16)Wp[(s * 32 + llk * 8 + j) * D + cc];
    wlds[c][s][ln] = v;
  }
  __syncthreads();

  bf16x8 wf[4][4];
  #pragma unroll
  for (int c = 0; c < 4; ++c)
    #pragma unroll
    for (int s = 0; s < 4; ++s)
      wf[c][s] = wlds[c][s][lane];

  // A fragments from x (f32 -> bf16)
  bf16x8 af[4];
  const float* xr = x + (size_t)(r0 + lr) * T;
  #pragma unroll
  for (int s = 0; s < 4; ++s) {
    const int t0 = s * 32 + lk * 8;
    const f32x4 v0 = *reinterpret_cast<const f32x4*>(xr + t0);
    const f32x4 v1 = *reinterpret_cast<const f32x4*>(xr + t0 + 4);
    #pragma unroll
    for (int j = 0; j < 4; ++j) {
      af[s][j]     = (__bf16)v0[j];
      af[s][4 + j] = (__bf16)v1[j];
    }
  }

  // MFMA with bias in C-in
  f32x4 pv[4];
  #pragma unroll
  for (int c = 0; c < 4; ++c) {
    const float* bp = (c < 2) ? b1 : b2;
    const float bv = bp[(c * 16 + lr) & 31];
    f32x4 accv = {bv, bv, bv, bv};
    #pragma unroll
    for (int s = 0; s < 4; ++s)
      accv = __builtin_amdgcn_mfma_f32_16x16x32_bf16(af[s], wf[c][s], accv, 0, 0, 0);
    pv[c] = accv;
  }

  // store p (p1 pre-scaled by M2)
  #pragma unroll
  for (int c = 0; c < 2; ++c)
    #pragma unroll
    for (int r = 0; r < 4; ++r)
      p1b[(size_t)(r0 + lk * 4 + r) * D + c * 16 + lr] = (__bf16)(M2 * pv[c][r]);
  #pragma unroll
  for (int c = 2; c < 4; ++c)
    #pragma unroll
    for (int r = 0; r < 4; ++r)
      p2b[(size_t)(r0 + lk * 4 + r) * D + (c - 2) * 16 + lr] = (__bf16)pv[c][r];

  // row squared norms: reduce over the 16 col-lanes
  float q1[4], q2[4];
  #pragma unroll
  for (int r = 0; r < 4; ++r) {
    q1[r] = fmaf(pv[0][r], pv[0][r], pv[1][r] * pv[1][r]);
    q2[r] = fmaf(pv[2][r], pv[2][r], pv[3][r] * pv[3][r]);
  }
  #pragma unroll
  for (int m = 1; m < 16; m <<= 1)
    #pragma unroll
    for (int r = 0; r < 4; ++r) {
      q1[r] += __shfl_xor(q1[r], m, 64);
      q2[r] += __shfl_xor(q2[r], m, 64);
    }
  if (lr == 0) {
    #pragma unroll
    for (int r = 0; r < 4; ++r) {
      const int row = r0 + lk * 4 + r;
      s1[row] = K2 * q1[r];
      e2[row] = 0.125f * exp2_fast(K2 * q2[r]);
    }
  }
}

// ---------------------------------------------------------------------------
// Kernel 2: acc(i,j) = sum_b e2[b,j] * exp2( M2*dot + K2*sq1 ).
// Wave computes 32x64 tile; block = 4 waves = 128x64.
// v3: explicit 1-deep double-buffered prefetch over the batch loop.
// ---------------------------------------------------------------------------
__global__ __launch_bounds__(256, 3) void fused_kernel(
    const __bf16* __restrict__ p1b, const __bf16* __restrict__ p2b,
    const float* __restrict__ s1,   const float* __restrict__ e2,
    float* __restrict__ out) {
  const int lane = threadIdx.x & 63;
  const int wid  = threadIdx.x >> 6;
  const int j0 = blockIdx.x * 64;
  const int i0 = blockIdx.y * 128 + wid * 32;
  const int lr = lane & 15;
  const int lk = lane >> 4;

  const __bf16* pa = p1b + (size_t)(i0 + lr) * D + lk * 8;
  const __bf16* pb = p2b + (size_t)(j0 + lr) * D + lk * 8;
  const float*  ps = s1 + i0 + lk * 4;
  const float*  pe = e2 + j0 + lr;

  bf16x8 A[2][2], Bf[2][4];
  f32x4  S[2][2];
  float  E[2][4];

  f32x4 acc[2][4];
  #pragma unroll
  for (int a = 0; a < 2; ++a)
    #pragma unroll
    for (int c = 0; c < 4; ++c)
      acc[a][c] = f32x4{0.f, 0.f, 0.f, 0.f};

#define LOADF(bb, q)                                                          \
  {                                                                           \
    const size_t ob = (size_t)(bb) * (N * D);                                 \
    const size_t os = (size_t)(bb) * N;                                       \
    _Pragma("unroll")                                                         \
    for (int a = 0; a < 2; ++a)                                               \
      A[q][a] = *reinterpret_cast<const bf16x8*>(pa + ob + a * 16 * D);       \
    _Pragma("unroll")                                                         \
    for (int c = 0; c < 4; ++c)                                               \
      Bf[q][c] = *reinterpret_cast<const bf16x8*>(pb + ob + c * 16 * D);      \
    _Pragma("unroll")                                                         \
    for (int a = 0; a < 2; ++a)                                               \
      S[q][a] = *reinterpret_cast<const f32x4*>(ps + os + a * 16);            \
    _Pragma("unroll")                                                         \
    for (int c = 0; c < 4; ++c)                                               \
      E[q][c] = pe[os + c * 16];                                              \
  }

  LOADF(0, 0)
  #pragma unroll
  for (int b = 0; b < B; ++b) {
    const int cur = b & 1;       // static after full unroll
    if (b + 1 < B) LOADF(b + 1, (cur ^ 1))
    #pragma unroll
    for (int a = 0; a < 2; ++a) {
      #pragma unroll
      for (int c = 0; c < 4; ++c) {
        f32x4 t = __builtin_amdgcn_mfma_f32_16x16x32_bf16(
            A[cur][a], Bf[cur][c], S[cur][a], 0, 0, 0);
        #pragma unroll
        for (int r = 0; r < 4; ++r)
          acc[a][c][r] = fmaf(E[cur][c], exp2_fast(t[r]), acc[a][c][r]);
      }
    }
  }
#undef LOADF

  const bool hasdiag = (i0 < j0 + 64) && (j0 < i0 + 32);
  #pragma unroll
  for (int a = 0; a < 2; ++a) {
    #pragma unroll
    for (int c = 0; c < 4; ++c) {
      #pragma unroll
      for (int r = 0; r < 4; ++r) {
        const int row = i0 + a * 16 + lk * 4 + r;
        const int col = j0 + c * 16 + lr;
        float v = acc[a][c][r];
        if (hasdiag && row == col) v = 0.1f;
        out[(size_t)row * N + col] = v;
      }
    }
  }
}

extern "C" void kernel_launch(void* const* d_in, const int* in_sizes, int n_in,
                              void* d_out, int out_size, void* d_ws, size_t ws_size,
                              hipStream_t stream) {
  (void)in_sizes; (void)n_in; (void)out_size; (void)ws_size;
  const float* x  = (const float*)d_in[0];
  const float* W1 = (const float*)d_in[1];
  const float* b1 = (const float*)d_in[2];
  const float* W2 = (const float*)d_in[3];
  const float* b2 = (const float*)d_in[4];
  float* out = (float*)d_out;

  char* ws = (char*)d_ws;
  const size_t pbytes = (size_t)B * N * D * sizeof(__bf16);  // 2 MB each
  __bf16* p1b = (__bf16*)ws;
  __bf16* p2b = (__bf16*)(ws + pbytes);
  float*  s1  = (float*)(ws + 2 * pbytes);
  float*  e2  = (float*)(ws + 2 * pbytes + (size_t)B * N * sizeof(float));

  proj_mfma<<<(B * N) / 64, 256, 0, stream>>>(x, W1, b1, W2, b2, p1b, p2b, s1, e2);

  dim3 grid(N / 64, N / 128);
  fused_kernel<<<grid, 256, 0, stream>>>(p1b, p2b, s1, e2, out);
}

// Round 4
// 44.817 us; speedup vs baseline: 4.7621x; 4.7621x over previous
//
#include <hip/hip_runtime.h>
#include <hip/hip_bf16.h>

typedef __bf16 bf16x8 __attribute__((ext_vector_type(8)));
typedef float  f32x4  __attribute__((ext_vector_type(4)));

constexpr int B = 8, N = 4096, T = 128, D = 32;
constexpr float GAMMA = 0.001f;
constexpr float LOG2E = 1.4426950408889634f;
constexpr float K2 = -GAMMA * LOG2E;   // coeff on sq1 / sq2 (log2 domain)
constexpr float M2 = -2.0f * K2;       // coeff on dot

__device__ __forceinline__ float exp2_fast(float t) {
#if __has_builtin(__builtin_amdgcn_exp2f)
  return __builtin_amdgcn_exp2f(t);
#else
  return exp2f(t);
#endif
}

// ---------------------------------------------------------------------------
// Kernel 1 (MFMA proj): p1' = M2*(x@W1+b1) bf16, p2 = x@W2+b2 bf16,
// s1 = K2*||p1||^2, e2 = 0.125*exp2(K2*||p2||^2).
// W fragments staged once per block into LDS in frag-ready layout.
// ---------------------------------------------------------------------------
__global__ __launch_bounds__(256, 2) void proj_mfma(
    const float* __restrict__ x,  const float* __restrict__ W1,
    const float* __restrict__ b1, const float* __restrict__ W2,
    const float* __restrict__ b2,
    __bf16* __restrict__ p1b, __bf16* __restrict__ p2b,
    float* __restrict__ s1, float* __restrict__ e2) {
  __shared__ bf16x8 wlds[4][4][64];   // 16 KB, frag-ready
  const int tid  = threadIdx.x;
  const int lane = tid & 63;
  const int wid  = tid >> 6;
  const int lr   = lane & 15;
  const int lk   = lane >> 4;
  const int r0   = blockIdx.x * 64 + wid * 16;   // 0 .. B*N-1

  // cooperative W-frag fill: 1024 entries, 4 per thread
  #pragma unroll
  for (int t = 0; t < 4; ++t) {
    const int e  = tid + t * 256;
    const int c  = e >> 8;
    const int s  = (e >> 6) & 3;
    const int ln = e & 63;
    const int llr = ln & 15, llk = ln >> 4;
    const float* Wp = (c < 2) ? W1 : W2;
    const int cc = (c * 16 + llr) & 31;
    bf16x8 v;
    #pragma unroll
    for (int j = 0; j < 8; ++j)
      v[j] = (__bf16)Wp[(s * 32 + llk * 8 + j) * D + cc];
    wlds[c][s][ln] = v;
  }
  __syncthreads();

  bf16x8 wf[4][4];
  #pragma unroll
  for (int c = 0; c < 4; ++c)
    #pragma unroll
    for (int s = 0; s < 4; ++s)
      wf[c][s] = wlds[c][s][lane];

  // A fragments from x (f32 -> bf16)
  bf16x8 af[4];
  const float* xr = x + (size_t)(r0 + lr) * T;
  #pragma unroll
  for (int s = 0; s < 4; ++s) {
    const int t0 = s * 32 + lk * 8;
    const f32x4 v0 = *reinterpret_cast<const f32x4*>(xr + t0);
    const f32x4 v1 = *reinterpret_cast<const f32x4*>(xr + t0 + 4);
    #pragma unroll
    for (int j = 0; j < 4; ++j) {
      af[s][j]     = (__bf16)v0[j];
      af[s][4 + j] = (__bf16)v1[j];
    }
  }

  // MFMA with bias in C-in
  f32x4 pv[4];
  #pragma unroll
  for (int c = 0; c < 4; ++c) {
    const float* bp = (c < 2) ? b1 : b2;
    const float bv = bp[(c * 16 + lr) & 31];
    f32x4 accv = {bv, bv, bv, bv};
    #pragma unroll
    for (int s = 0; s < 4; ++s)
      accv = __builtin_amdgcn_mfma_f32_16x16x32_bf16(af[s], wf[c][s], accv, 0, 0, 0);
    pv[c] = accv;
  }

  // store p (p1 pre-scaled by M2)
  #pragma unroll
  for (int c = 0; c < 2; ++c)
    #pragma unroll
    for (int r = 0; r < 4; ++r)
      p1b[(size_t)(r0 + lk * 4 + r) * D + c * 16 + lr] = (__bf16)(M2 * pv[c][r]);
  #pragma unroll
  for (int c = 2; c < 4; ++c)
    #pragma unroll
    for (int r = 0; r < 4; ++r)
      p2b[(size_t)(r0 + lk * 4 + r) * D + (c - 2) * 16 + lr] = (__bf16)pv[c][r];

  // row squared norms: reduce over the 16 col-lanes
  float q1[4], q2[4];
  #pragma unroll
  for (int r = 0; r < 4; ++r) {
    q1[r] = fmaf(pv[0][r], pv[0][r], pv[1][r] * pv[1][r]);
    q2[r] = fmaf(pv[2][r], pv[2][r], pv[3][r] * pv[3][r]);
  }
  #pragma unroll
  for (int m = 1; m < 16; m <<= 1)
    #pragma unroll
    for (int r = 0; r < 4; ++r) {
      q1[r] += __shfl_xor(q1[r], m, 64);
      q2[r] += __shfl_xor(q2[r], m, 64);
    }
  if (lr == 0) {
    #pragma unroll
    for (int r = 0; r < 4; ++r) {
      const int row = r0 + lk * 4 + r;
      s1[row] = K2 * q1[r];
      e2[row] = 0.125f * exp2_fast(K2 * q2[r]);
    }
  }
}

// ---------------------------------------------------------------------------
// Kernel 2: acc(i,j) = sum_b e2[b,j] * exp2( M2*dot + K2*sq1 ).
// Wave computes 32x64 tile; block = 4 waves = 128x64.
// v4: 2-deep software pipeline with TWO NAMED fragment sets (fx, fy) and a
// textually alternated schedule — every array index is a compile-time
// constant (rule #20: runtime-indexed ext_vector arrays go to scratch;
// v3's [cur] indexing caused 760 MB of spill traffic).
// ---------------------------------------------------------------------------
struct Frag {
  bf16x8 A[2];
  bf16x8 Bf[4];
  f32x4  S[2];
  float  E[4];
};

__global__ __launch_bounds__(256, 3) void fused_kernel(
    const __bf16* __restrict__ p1b, const __bf16* __restrict__ p2b,
    const float* __restrict__ s1,   const float* __restrict__ e2,
    float* __restrict__ out) {
  const int lane = threadIdx.x & 63;
  const int wid  = threadIdx.x >> 6;
  const int j0 = blockIdx.x * 64;
  const int i0 = blockIdx.y * 128 + wid * 32;
  const int lr = lane & 15;
  const int lk = lane >> 4;

  const __bf16* pa = p1b + (size_t)(i0 + lr) * D + lk * 8;
  const __bf16* pb = p2b + (size_t)(j0 + lr) * D + lk * 8;
  const float*  ps = s1 + i0 + lk * 4;
  const float*  pe = e2 + j0 + lr;

  f32x4 acc[2][4];
  #pragma unroll
  for (int a = 0; a < 2; ++a)
    #pragma unroll
    for (int c = 0; c < 4; ++c)
      acc[a][c] = f32x4{0.f, 0.f, 0.f, 0.f};

  Frag fx, fy;

  auto load = [&](Frag& f, int bb) __attribute__((always_inline)) {
    const size_t ob = (size_t)bb * (N * D);
    const size_t os = (size_t)bb * N;
    #pragma unroll
    for (int a = 0; a < 2; ++a)
      f.A[a] = *reinterpret_cast<const bf16x8*>(pa + ob + a * (16 * D));
    #pragma unroll
    for (int c = 0; c < 4; ++c)
      f.Bf[c] = *reinterpret_cast<const bf16x8*>(pb + ob + c * (16 * D));
    #pragma unroll
    for (int a = 0; a < 2; ++a)
      f.S[a] = *reinterpret_cast<const f32x4*>(ps + os + a * 16);
    #pragma unroll
    for (int c = 0; c < 4; ++c)
      f.E[c] = pe[os + c * 16];
  };

  auto compute = [&](const Frag& f) __attribute__((always_inline)) {
    #pragma unroll
    for (int a = 0; a < 2; ++a) {
      #pragma unroll
      for (int c = 0; c < 4; ++c) {
        f32x4 t = __builtin_amdgcn_mfma_f32_16x16x32_bf16(
            f.A[a], f.Bf[c], f.S[a], 0, 0, 0);
        #pragma unroll
        for (int r = 0; r < 4; ++r)
          acc[a][c][r] = fmaf(f.E[c], exp2_fast(t[r]), acc[a][c][r]);
      }
    }
  };

  // textually unrolled 2-deep pipeline over B=8 batches
  load(fx, 0);
  load(fy, 1);
  compute(fx);
  load(fx, 2);
  compute(fy);
  load(fy, 3);
  compute(fx);
  load(fx, 4);
  compute(fy);
  load(fy, 5);
  compute(fx);
  load(fx, 6);
  compute(fy);
  load(fy, 7);
  compute(fx);
  compute(fy);

  const bool hasdiag = (i0 < j0 + 64) && (j0 < i0 + 32);
  #pragma unroll
  for (int a = 0; a < 2; ++a) {
    #pragma unroll
    for (int c = 0; c < 4; ++c) {
      #pragma unroll
      for (int r = 0; r < 4; ++r) {
        const int row = i0 + a * 16 + lk * 4 + r;
        const int col = j0 + c * 16 + lr;
        float v = acc[a][c][r];
        if (hasdiag && row == col) v = 0.1f;
        __builtin_nontemporal_store(v, &out[(size_t)row * N + col]);
      }
    }
  }
}

extern "C" void kernel_launch(void* const* d_in, const int* in_sizes, int n_in,
                              void* d_out, int out_size, void* d_ws, size_t ws_size,
                              hipStream_t stream) {
  (void)in_sizes; (void)n_in; (void)out_size; (void)ws_size;
  const float* x  = (const float*)d_in[0];
  const float* W1 = (const float*)d_in[1];
  const float* b1 = (const float*)d_in[2];
  const float* W2 = (const float*)d_in[3];
  const float* b2 = (const float*)d_in[4];
  float* out = (float*)d_out;

  char* ws = (char*)d_ws;
  const size_t pbytes = (size_t)B * N * D * sizeof(__bf16);  // 2 MB each
  __bf16* p1b = (__bf16*)ws;
  __bf16* p2b = (__bf16*)(ws + pbytes);
  float*  s1  = (float*)(ws + 2 * pbytes);
  float*  e2  = (float*)(ws + 2 * pbytes + (size_t)B * N * sizeof(float));

  proj_mfma<<<(B * N) / 64, 256, 0, stream>>>(x, W1, b1, W2, b2, p1b, p2b, s1, e2);

  dim3 grid(N / 64, N / 128);
  fused_kernel<<<grid, 256, 0, stream>>>(p1b, p2b, s1, e2, out);
}